// Round 3
// baseline (2616.153 us; speedup 1.0000x reference)
//
#include <hip/hip_runtime.h>

// Problem constants (from reference setup_inputs)
#define KK   27
#define MM   80000
#define NN   200000
#define INC  64
#define OUTC 128
#define RIN  48
#define ROUT 96

#define BLOCKS_PER_K 80
#define ENTRIES_PER_BLOCK ((MM + BLOCKS_PER_K - 1) / BLOCKS_PER_K)  // 1000

#define SCAN_CHUNK 1024
#define NB_BLOCKS ((NN + SCAN_CHUNK - 1) / SCAN_CHUNK)  // 196

// ---------------------------------------------------------------------------
// Fallback: single-pass atomic scatter (R1 kernel, known-good, ~1.66 ms)
// ---------------------------------------------------------------------------
__global__ __launch_bounds__(192)
void sparse_conv_scatter(const float* __restrict__ feat,
                         const float* __restrict__ w,
                         const int* __restrict__ imap,
                         const int* __restrict__ omap,
                         float* __restrict__ out)
{
    __shared__ float wlds[RIN * ROUT];
    const int k = blockIdx.y;
    const float* wk = w + (size_t)k * INC * OUTC;
    for (int idx = threadIdx.x; idx < RIN * ROUT; idx += 192) {
        int i = idx / ROUT;
        int o = idx - i * ROUT;
        wlds[idx] = wk[i * OUTC + o];
    }
    __syncthreads();

    const int sub = threadIdx.x / 96;
    const int oc  = threadIdx.x % 96;
    const int m0 = blockIdx.x * ENTRIES_PER_BLOCK;
    const int m1 = min(m0 + ENTRIES_PER_BLOCK, MM);
    const int* imk = imap + (size_t)k * MM;
    const int* omk = omap + (size_t)k * MM;

    for (int m = m0 + sub; m < m1; m += 2) {
        const int fin  = imk[m];
        const int fout = omk[m];
        const float4* f4 = (const float4*)(feat + (size_t)fin * RIN);
        float acc = 0.f;
        #pragma unroll
        for (int i4 = 0; i4 < RIN / 4; ++i4) {
            float4 v = f4[i4];
            acc += v.x * wlds[(i4 * 4 + 0) * ROUT + oc];
            acc += v.y * wlds[(i4 * 4 + 1) * ROUT + oc];
            acc += v.z * wlds[(i4 * 4 + 2) * ROUT + oc];
            acc += v.w * wlds[(i4 * 4 + 3) * ROUT + oc];
        }
        atomicAdd(&out[(size_t)fout * ROUT + oc], acc);
    }
}

// ---------------------------------------------------------------------------
// CSR build
// ---------------------------------------------------------------------------
__global__ __launch_bounds__(256)
void count_kernel(const int* __restrict__ omap_base, int Eg, int* __restrict__ cnt)
{
    int e = blockIdx.x * 256 + threadIdx.x;
    if (e < Eg) atomicAdd(&cnt[omap_base[e]], 1);
}

// per-block sums of 1024-element chunks
__global__ __launch_bounds__(256)
void scan_part(const int* __restrict__ cnt, int* __restrict__ bsum)
{
    __shared__ int sh[256];
    int t = threadIdx.x;
    int base = blockIdx.x * SCAN_CHUNK + t * 4;
    int s = 0;
    #pragma unroll
    for (int j = 0; j < 4; ++j)
        if (base + j < NN) s += cnt[base + j];
    sh[t] = s;
    __syncthreads();
    for (int off = 128; off > 0; off >>= 1) {
        if (t < off) sh[t] += sh[t + off];
        __syncthreads();
    }
    if (t == 0) bsum[blockIdx.x] = sh[0];
}

// exclusive scan of bsum (NB_BLOCKS <= 256), in place
__global__ __launch_bounds__(256)
void scan_bsum(int* __restrict__ bsum)
{
    __shared__ int sh[256];
    int t = threadIdx.x;
    int v = (t < NB_BLOCKS) ? bsum[t] : 0;
    sh[t] = v;
    __syncthreads();
    for (int off = 1; off < 256; off <<= 1) {
        int x = (t >= off) ? sh[t - off] : 0;
        __syncthreads();
        sh[t] += x;
        __syncthreads();
    }
    if (t < NB_BLOCKS) bsum[t] = sh[t] - v;   // exclusive
}

// final: per-element exclusive scan -> offs, copy to cursor (aliases cnt)
__global__ __launch_bounds__(256)
void scan_final(int* __restrict__ cnt /*also cursor out*/,
                const int* __restrict__ bsum,
                int* __restrict__ offs, int Eg)
{
    __shared__ int sh[256];
    int t = threadIdx.x;
    int base = blockIdx.x * SCAN_CHUNK + t * 4;
    int v[4];
    int s = 0;
    #pragma unroll
    for (int j = 0; j < 4; ++j) {
        v[j] = (base + j < NN) ? cnt[base + j] : 0;
        s += v[j];
    }
    sh[t] = s;
    __syncthreads();
    for (int off = 1; off < 256; off <<= 1) {
        int x = (t >= off) ? sh[t - off] : 0;
        __syncthreads();
        sh[t] += x;
        __syncthreads();
    }
    int run = sh[t] - s + bsum[blockIdx.x];
    #pragma unroll
    for (int j = 0; j < 4; ++j) {
        if (base + j < NN) {
            offs[base + j] = run;
            cnt[base + j]  = run;   // cursor
            run += v[j];
        }
    }
    if (blockIdx.x == 0 && t == 0) offs[NN] = Eg;
}

__global__ __launch_bounds__(256)
void fill_kernel(const int* __restrict__ omap_base, int Eg,
                 int* __restrict__ cursor, int* __restrict__ elist)
{
    int e = blockIdx.x * 256 + threadIdx.x;
    if (e < Eg) {
        int r = omap_base[e];
        int p = atomicAdd(&cursor[r], 1);
        elist[p] = e;
    }
}

// ---------------------------------------------------------------------------
// Stage 1: dense contribution compute (no scatter). k is block-uniform.
// ---------------------------------------------------------------------------
__global__ __launch_bounds__(192)
void stage1_compute(const float* __restrict__ feat,
                    const float* __restrict__ w,
                    const int* __restrict__ imap,
                    int k0,
                    float* __restrict__ contrib)
{
    const int klocal = blockIdx.y;
    const int k      = k0 + klocal;
    const int oc  = threadIdx.x % 96;
    const int sub = threadIdx.x / 96;

    const float* wk = w + (size_t)k * INC * OUTC + oc;
    float wr[RIN];
    #pragma unroll
    for (int i = 0; i < RIN; ++i) wr[i] = wk[(size_t)i * OUTC];

    const int m0 = blockIdx.x * ENTRIES_PER_BLOCK;
    const int m1 = min(m0 + ENTRIES_PER_BLOCK, MM);
    const int* imk = imap + (size_t)k * MM;

    for (int m = m0 + sub; m < m1; m += 2) {
        const int fin = imk[m];
        const float4* f4 = (const float4*)(feat + (size_t)fin * RIN);
        float acc = 0.f;
        #pragma unroll
        for (int j = 0; j < RIN / 4; ++j) {
            float4 v = f4[j];
            acc += v.x * wr[4 * j + 0];
            acc += v.y * wr[4 * j + 1];
            acc += v.z * wr[4 * j + 2];
            acc += v.w * wr[4 * j + 3];
        }
        contrib[((size_t)klocal * MM + m) * ROUT + oc] = acc;
    }
}

// ---------------------------------------------------------------------------
// Stage 2: per-row gather-reduce, single non-atomic write per element.
// ---------------------------------------------------------------------------
__global__ __launch_bounds__(192)
void stage2_gather(const float* __restrict__ contrib,
                   const int* __restrict__ offs,
                   const int* __restrict__ elist,
                   float* __restrict__ out,
                   int accumulate)
{
    const int sub = threadIdx.x / 96;
    const int oc  = threadIdx.x % 96;
    const int r = blockIdx.x * 2 + sub;
    if (r >= NN) return;

    const int j0 = offs[r];
    const int j1 = offs[r + 1];
    if (j0 == j1) return;

    float acc = 0.f;
    for (int j = j0; j < j1; ++j) {
        const int e = elist[j];
        acc += contrib[(size_t)e * ROUT + oc];
    }
    const size_t idx = (size_t)r * ROUT + oc;
    if (accumulate) out[idx] += acc;
    else            out[idx]  = acc;
}

// ---------------------------------------------------------------------------
extern "C" void kernel_launch(void* const* d_in, const int* in_sizes, int n_in,
                              void* d_out, int out_size, void* d_ws, size_t ws_size,
                              hipStream_t stream)
{
    const float* features = (const float*)d_in[0];
    const float* kernel_w = (const float*)d_in[1];
    const int*   in_map   = (const int*)d_in[2];
    const int*   out_map  = (const int*)d_in[3];
    float*       out      = (float*)d_out;

    hipMemsetAsync(d_out, 0, (size_t)out_size * sizeof(float), stream);

    // workspace layout (256B-aligned sections)
    const size_t off_cnt  = 0;                          // N ints (cnt, then cursor)
    const size_t off_offs = 800000;                     // (N+1) ints
    const size_t off_bsum = off_offs + 800256;          // NB ints (padded to 1024)
    const size_t base     = off_bsum + 1024;            // elist + contrib from here
    // per-k cost: elist M ints + contrib M*96 floats = M*(4+384) bytes
    const size_t per_k = (size_t)MM * (4 + ROUT * 4);

    int gcap = 0;
    if (ws_size > base) gcap = (int)((ws_size - base) / per_k);
    if (gcap > KK) gcap = KK;

    if (gcap < 4) {
        // not enough scratch for an efficient two-phase run -> atomic fallback
        dim3 grid(BLOCKS_PER_K, KK);
        sparse_conv_scatter<<<grid, 192, 0, stream>>>(features, kernel_w, in_map, out_map, out);
        return;
    }

    char* ws = (char*)d_ws;
    int*   cnt     = (int*)(ws + off_cnt);
    int*   offs    = (int*)(ws + off_offs);
    int*   bsum    = (int*)(ws + off_bsum);
    int*   elist   = (int*)(ws + base);
    float* contrib = (float*)(ws + base + (size_t)gcap * MM * 4);

    const int ngroups = (KK + gcap - 1) / gcap;

    for (int g = 0; g < ngroups; ++g) {
        const int k0 = g * gcap;
        const int gk = min(gcap, KK - k0);
        const int Eg = gk * MM;
        const int* omap_base = out_map + (size_t)k0 * MM;

        hipMemsetAsync(cnt, 0, (size_t)NN * sizeof(int), stream);
        count_kernel<<<(Eg + 255) / 256, 256, 0, stream>>>(omap_base, Eg, cnt);
        scan_part<<<NB_BLOCKS, 256, 0, stream>>>(cnt, bsum);
        scan_bsum<<<1, 256, 0, stream>>>(bsum);
        scan_final<<<NB_BLOCKS, 256, 0, stream>>>(cnt, bsum, offs, Eg);
        fill_kernel<<<(Eg + 255) / 256, 256, 0, stream>>>(omap_base, Eg, cnt, elist);

        dim3 g1(BLOCKS_PER_K, gk);
        stage1_compute<<<g1, 192, 0, stream>>>(features, kernel_w, in_map, k0, contrib);

        stage2_gather<<<(NN + 1) / 2, 192, 0, stream>>>(contrib, offs, elist, out, g > 0 ? 1 : 0);
    }
}

// Round 4
// 1830.360 us; speedup vs baseline: 1.4293x; 1.4293x over previous
//
#include <hip/hip_runtime.h>
#include <hip/hip_bf16.h>

// Problem constants (from reference setup_inputs)
#define KK   27
#define MM   80000
#define NN   200000
#define INC  64
#define OUTC 128
#define RIN  48
#define ROUT 96

#define BLOCKS_PER_K 200
#define ENTRIES_PER_BLOCK ((MM + BLOCKS_PER_K - 1) / BLOCKS_PER_K)  // 400

#define SCAN_CHUNK 1024
#define NB_BLOCKS ((NN + SCAN_CHUNK - 1) / SCAN_CHUNK)  // 196

// ---------------------------------------------------------------------------
// Fallback: single-pass atomic scatter (R1 kernel, known-good, ~1.66 ms)
// ---------------------------------------------------------------------------
__global__ __launch_bounds__(192)
void sparse_conv_scatter(const float* __restrict__ feat,
                         const float* __restrict__ w,
                         const int* __restrict__ imap,
                         const int* __restrict__ omap,
                         float* __restrict__ out)
{
    __shared__ float wlds[RIN * ROUT];
    const int k = blockIdx.y;
    const float* wk = w + (size_t)k * INC * OUTC;
    for (int idx = threadIdx.x; idx < RIN * ROUT; idx += 192) {
        int i = idx / ROUT;
        int o = idx - i * ROUT;
        wlds[idx] = wk[i * OUTC + o];
    }
    __syncthreads();

    const int sub = threadIdx.x / 96;
    const int oc  = threadIdx.x % 96;
    const int m0 = blockIdx.x * ENTRIES_PER_BLOCK;
    const int m1 = min(m0 + ENTRIES_PER_BLOCK, MM);
    const int* imk = imap + (size_t)k * MM;
    const int* omk = omap + (size_t)k * MM;

    for (int m = m0 + sub; m < m1; m += 2) {
        const int fin  = imk[m];
        const int fout = omk[m];
        const float4* f4 = (const float4*)(feat + (size_t)fin * RIN);
        float acc = 0.f;
        #pragma unroll
        for (int i4 = 0; i4 < RIN / 4; ++i4) {
            float4 v = f4[i4];
            acc += v.x * wlds[(i4 * 4 + 0) * ROUT + oc];
            acc += v.y * wlds[(i4 * 4 + 1) * ROUT + oc];
            acc += v.z * wlds[(i4 * 4 + 2) * ROUT + oc];
            acc += v.w * wlds[(i4 * 4 + 3) * ROUT + oc];
        }
        atomicAdd(&out[(size_t)fout * ROUT + oc], acc);
    }
}

// ---------------------------------------------------------------------------
// CSR build
// ---------------------------------------------------------------------------
__global__ __launch_bounds__(256)
void count_kernel(const int* __restrict__ omap_base, int Eg, int* __restrict__ cnt)
{
    int e = blockIdx.x * 256 + threadIdx.x;
    if (e < Eg) atomicAdd(&cnt[omap_base[e]], 1);
}

__global__ __launch_bounds__(256)
void scan_part(const int* __restrict__ cnt, int* __restrict__ bsum)
{
    __shared__ int sh[256];
    int t = threadIdx.x;
    int base = blockIdx.x * SCAN_CHUNK + t * 4;
    int s = 0;
    #pragma unroll
    for (int j = 0; j < 4; ++j)
        if (base + j < NN) s += cnt[base + j];
    sh[t] = s;
    __syncthreads();
    for (int off = 128; off > 0; off >>= 1) {
        if (t < off) sh[t] += sh[t + off];
        __syncthreads();
    }
    if (t == 0) bsum[blockIdx.x] = sh[0];
}

__global__ __launch_bounds__(256)
void scan_bsum(int* __restrict__ bsum)
{
    __shared__ int sh[256];
    int t = threadIdx.x;
    int v = (t < NB_BLOCKS) ? bsum[t] : 0;
    sh[t] = v;
    __syncthreads();
    for (int off = 1; off < 256; off <<= 1) {
        int x = (t >= off) ? sh[t - off] : 0;
        __syncthreads();
        sh[t] += x;
        __syncthreads();
    }
    if (t < NB_BLOCKS) bsum[t] = sh[t] - v;   // exclusive
}

__global__ __launch_bounds__(256)
void scan_final(int* __restrict__ cnt /*also cursor out*/,
                const int* __restrict__ bsum,
                int* __restrict__ offs, int Eg)
{
    __shared__ int sh[256];
    int t = threadIdx.x;
    int base = blockIdx.x * SCAN_CHUNK + t * 4;
    int v[4];
    int s = 0;
    #pragma unroll
    for (int j = 0; j < 4; ++j) {
        v[j] = (base + j < NN) ? cnt[base + j] : 0;
        s += v[j];
    }
    sh[t] = s;
    __syncthreads();
    for (int off = 1; off < 256; off <<= 1) {
        int x = (t >= off) ? sh[t - off] : 0;
        __syncthreads();
        sh[t] += x;
        __syncthreads();
    }
    int run = sh[t] - s + bsum[blockIdx.x];
    #pragma unroll
    for (int j = 0; j < 4; ++j) {
        if (base + j < NN) {
            offs[base + j] = run;
            cnt[base + j]  = run;   // cursor
            run += v[j];
        }
    }
    if (blockIdx.x == 0 && t == 0) offs[NN] = Eg;
}

// fill: pos[e] = CSR slot of entry e (coalesced write; no elist needed)
__global__ __launch_bounds__(256)
void fill_kernel(const int* __restrict__ omap_base, int Eg,
                 int* __restrict__ cursor, int* __restrict__ pos)
{
    int e = blockIdx.x * 256 + threadIdx.x;
    if (e < Eg) {
        int r = omap_base[e];
        pos[e] = atomicAdd(&cursor[r], 1);
    }
}

// ---------------------------------------------------------------------------
// Stage 1: dense contribution compute, written in CSR order as bf16.
// ---------------------------------------------------------------------------
__global__ __launch_bounds__(192)
void stage1_compute(const float* __restrict__ feat,
                    const float* __restrict__ w,
                    const int* __restrict__ imap,
                    const int* __restrict__ pos,
                    int k0,
                    __hip_bfloat16* __restrict__ contrib)
{
    const int klocal = blockIdx.y;
    const int k      = k0 + klocal;
    const int oc  = threadIdx.x % 96;
    const int sub = threadIdx.x / 96;

    // weight column w[k][0..47][oc] in registers
    const float* wk = w + (size_t)k * INC * OUTC + oc;
    float wr[RIN];
    #pragma unroll
    for (int i = 0; i < RIN; ++i) wr[i] = wk[(size_t)i * OUTC];

    const int m0 = blockIdx.x * ENTRIES_PER_BLOCK;
    const int m1 = min(m0 + ENTRIES_PER_BLOCK, MM);
    const int* imk  = imap + (size_t)k * MM;
    const int* posk = pos + (size_t)klocal * MM;

    for (int m = m0 + sub; m < m1; m += 2) {
        const int fin = imk[m];
        const int p   = posk[m];
        const float4* f4 = (const float4*)(feat + (size_t)fin * RIN);
        float acc = 0.f;
        #pragma unroll
        for (int j = 0; j < RIN / 4; ++j) {
            float4 v = f4[j];
            acc += v.x * wr[4 * j + 0];
            acc += v.y * wr[4 * j + 1];
            acc += v.z * wr[4 * j + 2];
            acc += v.w * wr[4 * j + 3];
        }
        contrib[(size_t)p * ROUT + oc] = __float2bfloat16(acc);
    }
}

// ---------------------------------------------------------------------------
// Stage 2: per-row contiguous reduce over CSR slab, single write per element.
// ---------------------------------------------------------------------------
__global__ __launch_bounds__(192)
void stage2_gather(const __hip_bfloat16* __restrict__ contrib,
                   const int* __restrict__ offs,
                   float* __restrict__ out,
                   int accumulate)
{
    const int sub = threadIdx.x / 96;
    const int oc  = threadIdx.x % 96;
    const int r = blockIdx.x * 2 + sub;
    if (r >= NN) return;

    const int j0 = offs[r];
    const int j1 = offs[r + 1];
    if (j0 == j1) return;

    float acc0 = 0.f, acc1 = 0.f;
    int j = j0;
    for (; j + 1 < j1; j += 2) {
        acc0 += __bfloat162float(contrib[(size_t)j * ROUT + oc]);
        acc1 += __bfloat162float(contrib[(size_t)(j + 1) * ROUT + oc]);
    }
    if (j < j1) acc0 += __bfloat162float(contrib[(size_t)j * ROUT + oc]);

    const size_t idx = (size_t)r * ROUT + oc;
    float acc = acc0 + acc1;
    if (accumulate) out[idx] += acc;
    else            out[idx]  = acc;
}

// ---------------------------------------------------------------------------
extern "C" void kernel_launch(void* const* d_in, const int* in_sizes, int n_in,
                              void* d_out, int out_size, void* d_ws, size_t ws_size,
                              hipStream_t stream)
{
    const float* features = (const float*)d_in[0];
    const float* kernel_w = (const float*)d_in[1];
    const int*   in_map   = (const int*)d_in[2];
    const int*   out_map  = (const int*)d_in[3];
    float*       out      = (float*)d_out;

    hipMemsetAsync(d_out, 0, (size_t)out_size * sizeof(float), stream);

    // workspace layout
    const size_t off_cnt  = 0;                       // N ints (cnt -> cursor)
    const size_t off_offs = 800000;                  // (N+1) ints (800256 padded)
    const size_t off_bsum = off_offs + 800256;       // NB ints (1024 padded)
    const size_t base     = off_bsum + 1024;         // pos + contrib
    // per-k: pos M ints + contrib M*96 bf16 = M*(4+192) bytes
    const size_t per_k = (size_t)MM * (4 + ROUT * 2);   // 15,680,000

    int gcap = 0;
    if (ws_size > base) gcap = (int)((ws_size - base) / per_k);
    if (gcap > KK) gcap = KK;

    if (gcap < 2) {
        dim3 grid(BLOCKS_PER_K, KK);
        sparse_conv_scatter<<<grid, 192, 0, stream>>>(features, kernel_w, in_map, out_map, out);
        return;
    }

    char* ws = (char*)d_ws;
    int* cnt  = (int*)(ws + off_cnt);
    int* offs = (int*)(ws + off_offs);
    int* bsum = (int*)(ws + off_bsum);

    const int ngroups = (KK + gcap - 1) / gcap;

    int k0 = 0;
    for (int g = 0; g < ngroups; ++g) {
        // balanced split of KK across ngroups
        const int gk = KK / ngroups + (g < KK % ngroups ? 1 : 0);
        const int Eg = gk * MM;
        const int* omap_base = out_map + (size_t)k0 * MM;

        int*            pos     = (int*)(ws + base);
        __hip_bfloat16* contrib = (__hip_bfloat16*)(ws + base + (size_t)gk * MM * 4);

        hipMemsetAsync(cnt, 0, (size_t)NN * sizeof(int), stream);
        count_kernel<<<(Eg + 255) / 256, 256, 0, stream>>>(omap_base, Eg, cnt);
        scan_part<<<NB_BLOCKS, 256, 0, stream>>>(cnt, bsum);
        scan_bsum<<<1, 256, 0, stream>>>(bsum);
        scan_final<<<NB_BLOCKS, 256, 0, stream>>>(cnt, bsum, offs, Eg);
        fill_kernel<<<(Eg + 255) / 256, 256, 0, stream>>>(omap_base, Eg, cnt, pos);

        dim3 g1(BLOCKS_PER_K, gk);
        stage1_compute<<<g1, 192, 0, stream>>>(features, kernel_w, in_map, pos, k0, contrib);

        stage2_gather<<<(NN + 1) / 2, 192, 0, stream>>>(contrib, offs, out, g > 0 ? 1 : 0);

        k0 += gk;
    }
}

// Round 5
// 655.777 us; speedup vs baseline: 3.9894x; 2.7911x over previous
//
#include <hip/hip_runtime.h>
#include <hip/hip_bf16.h>

// Problem constants (from reference setup_inputs)
#define KK   27
#define MM   80000
#define NN   200000
#define INC  64
#define OUTC 128
#define RIN  48
#define ROUT 96

#define TILES_PER_K (MM / 16)          // 5000
#define S1_BLOCKS_PER_K 128            // 512 waves per k

#define SCAN_CHUNK 1024
#define NB_BLOCKS ((NN + SCAN_CHUNK - 1) / SCAN_CHUNK)  // 196

typedef __attribute__((ext_vector_type(8))) short bf16x8;  // 8 bf16 = 4 VGPR
typedef __attribute__((ext_vector_type(4))) float f32x4;

// ---------------------------------------------------------------------------
// Fallback: single-pass atomic scatter (R1 kernel, known-good, ~1.66 ms)
// ---------------------------------------------------------------------------
#define FB_BLOCKS_PER_K 200
#define FB_ENTRIES_PER_BLOCK ((MM + FB_BLOCKS_PER_K - 1) / FB_BLOCKS_PER_K)

__global__ __launch_bounds__(192)
void sparse_conv_scatter(const float* __restrict__ feat,
                         const float* __restrict__ w,
                         const int* __restrict__ imap,
                         const int* __restrict__ omap,
                         float* __restrict__ out)
{
    __shared__ float wlds[RIN * ROUT];
    const int k = blockIdx.y;
    const float* wk = w + (size_t)k * INC * OUTC;
    for (int idx = threadIdx.x; idx < RIN * ROUT; idx += 192) {
        int i = idx / ROUT;
        int o = idx - i * ROUT;
        wlds[idx] = wk[i * OUTC + o];
    }
    __syncthreads();

    const int sub = threadIdx.x / 96;
    const int oc  = threadIdx.x % 96;
    const int m0 = blockIdx.x * FB_ENTRIES_PER_BLOCK;
    const int m1 = min(m0 + FB_ENTRIES_PER_BLOCK, MM);
    const int* imk = imap + (size_t)k * MM;
    const int* omk = omap + (size_t)k * MM;

    for (int m = m0 + sub; m < m1; m += 2) {
        const int fin  = imk[m];
        const int fout = omk[m];
        const float4* f4 = (const float4*)(feat + (size_t)fin * RIN);
        float acc = 0.f;
        #pragma unroll
        for (int i4 = 0; i4 < RIN / 4; ++i4) {
            float4 v = f4[i4];
            acc += v.x * wlds[(i4 * 4 + 0) * ROUT + oc];
            acc += v.y * wlds[(i4 * 4 + 1) * ROUT + oc];
            acc += v.z * wlds[(i4 * 4 + 2) * ROUT + oc];
            acc += v.w * wlds[(i4 * 4 + 3) * ROUT + oc];
        }
        atomicAdd(&out[(size_t)fout * ROUT + oc], acc);
    }
}

// ---------------------------------------------------------------------------
// Precompute: features -> bf16, weights -> MFMA B-fragment pack
// ---------------------------------------------------------------------------
__global__ __launch_bounds__(256)
void feat_to_bf16(const float* __restrict__ f, __hip_bfloat16* __restrict__ fb)
{
    const size_t i = (size_t)blockIdx.x * 256 + threadIdx.x;   // one per 8 elems
    if (i >= (size_t)NN * RIN / 8) return;
    const float4* p = (const float4*)(f + i * 8);
    float4 a = p[0], b = p[1];
    union { __hip_bfloat16 h[8]; uint4 v; } o;
    o.h[0] = __float2bfloat16(a.x);
    o.h[1] = __float2bfloat16(a.y);
    o.h[2] = __float2bfloat16(a.z);
    o.h[3] = __float2bfloat16(a.w);
    o.h[4] = __float2bfloat16(b.x);
    o.h[5] = __float2bfloat16(b.y);
    o.h[6] = __float2bfloat16(b.z);
    o.h[7] = __float2bfloat16(b.w);
    ((uint4*)fb)[i] = o.v;
}

// wpack layout: frag f = oct*2 + ktile of kernel k lives at
//   bytes ((k*12 + f)*64 + lane)*16 ; lane supplies B[k=(lane>>4)*8+j][n=lane&15]
__global__ __launch_bounds__(64)
void build_wpack(const float* __restrict__ w, __hip_bfloat16* __restrict__ wp)
{
    const int b = blockIdx.x;          // k*12 + f,  f = oct*2 + ktile
    const int k = b / 12;
    const int f = b % 12;
    const int oct = f / 2, ktile = f % 2;
    const int lane = threadIdx.x;
    const int oc    = oct * 16 + (lane & 15);
    const int kbase = ktile * 32 + (lane >> 4) * 8;
    union { __hip_bfloat16 h[8]; uint4 v; } o;
    #pragma unroll
    for (int j = 0; j < 8; ++j) {
        int ki = kbase + j;
        float val = (ki < RIN) ? w[(size_t)k * INC * OUTC + (size_t)ki * OUTC + oc] : 0.f;
        o.h[j] = __float2bfloat16(val);
    }
    ((uint4*)wp)[(size_t)b * 64 + lane] = o.v;
}

// ---------------------------------------------------------------------------
// CSR build
// ---------------------------------------------------------------------------
__global__ __launch_bounds__(256)
void count_kernel(const int* __restrict__ omap_base, int Eg, int* __restrict__ cnt)
{
    int e = blockIdx.x * 256 + threadIdx.x;
    if (e < Eg) atomicAdd(&cnt[omap_base[e]], 1);
}

__global__ __launch_bounds__(256)
void scan_part(const int* __restrict__ cnt, int* __restrict__ bsum)
{
    __shared__ int sh[256];
    int t = threadIdx.x;
    int base = blockIdx.x * SCAN_CHUNK + t * 4;
    int s = 0;
    #pragma unroll
    for (int j = 0; j < 4; ++j)
        if (base + j < NN) s += cnt[base + j];
    sh[t] = s;
    __syncthreads();
    for (int off = 128; off > 0; off >>= 1) {
        if (t < off) sh[t] += sh[t + off];
        __syncthreads();
    }
    if (t == 0) bsum[blockIdx.x] = sh[0];
}

__global__ __launch_bounds__(256)
void scan_bsum(int* __restrict__ bsum)
{
    __shared__ int sh[256];
    int t = threadIdx.x;
    int v = (t < NB_BLOCKS) ? bsum[t] : 0;
    sh[t] = v;
    __syncthreads();
    for (int off = 1; off < 256; off <<= 1) {
        int x = (t >= off) ? sh[t - off] : 0;
        __syncthreads();
        sh[t] += x;
        __syncthreads();
    }
    if (t < NB_BLOCKS) bsum[t] = sh[t] - v;   // exclusive
}

__global__ __launch_bounds__(256)
void scan_final(int* __restrict__ cnt /*also cursor out*/,
                const int* __restrict__ bsum,
                int* __restrict__ offs, int Eg)
{
    __shared__ int sh[256];
    int t = threadIdx.x;
    int base = blockIdx.x * SCAN_CHUNK + t * 4;
    int v[4];
    int s = 0;
    #pragma unroll
    for (int j = 0; j < 4; ++j) {
        v[j] = (base + j < NN) ? cnt[base + j] : 0;
        s += v[j];
    }
    sh[t] = s;
    __syncthreads();
    for (int off = 1; off < 256; off <<= 1) {
        int x = (t >= off) ? sh[t - off] : 0;
        __syncthreads();
        sh[t] += x;
        __syncthreads();
    }
    int run = sh[t] - s + bsum[blockIdx.x];
    #pragma unroll
    for (int j = 0; j < 4; ++j) {
        if (base + j < NN) {
            offs[base + j] = run;
            cnt[base + j]  = run;   // cursor
            run += v[j];
        }
    }
    if (blockIdx.x == 0 && t == 0) offs[NN] = Eg;
}

__global__ __launch_bounds__(256)
void fill_kernel(const int* __restrict__ omap_base, int Eg,
                 int* __restrict__ cursor, int* __restrict__ pos)
{
    int e = blockIdx.x * 256 + threadIdx.x;
    if (e < Eg) {
        int r = omap_base[e];
        pos[e] = atomicAdd(&cursor[r], 1);
    }
}

// ---------------------------------------------------------------------------
// Stage 1 (MFMA): 16-entry x 96-oc contribution tiles, written in CSR order.
// One wave per tile-stream; A gathered from bf16 features, B from wpack.
// ---------------------------------------------------------------------------
__global__ __launch_bounds__(256)
void stage1_mfma(const __hip_bfloat16* __restrict__ fb,
                 const __hip_bfloat16* __restrict__ wp,
                 const int* __restrict__ imap,
                 const int* __restrict__ pos,
                 int k0,
                 __hip_bfloat16* __restrict__ contrib)
{
    const int klocal = blockIdx.y;
    const int k      = k0 + klocal;
    const int wid  = threadIdx.x >> 6;
    const int lane = threadIdx.x & 63;
    const int lo = lane & 15, hi = lane >> 4;

    // B fragments for this k (zero-padded to K=64): 12 x 16B per lane
    bf16x8 B[12];
    #pragma unroll
    for (int f = 0; f < 12; ++f)
        B[f] = *reinterpret_cast<const bf16x8*>(
            (const char*)wp + (((size_t)k * 12 + f) * 64 + lane) * 16);

    const int* imk  = imap + (size_t)k * MM;
    const int* posk = pos + (size_t)klocal * MM;

    const int wstride = gridDim.x * 4;
    int tile = blockIdx.x * 4 + wid;
    if (tile >= TILES_PER_K) return;

    // prologue: load tile's row + A frags
    int row = imk[tile * 16 + lo];
    bf16x8 A0 = *reinterpret_cast<const bf16x8*>((const char*)fb + (size_t)row * 96 + hi * 16);
    bf16x8 A1 = *reinterpret_cast<const bf16x8*>((const char*)fb + (size_t)row * 96 + 64 + hi * 16);
    // (hi>=2 reads of A1 are past k=48 -> garbage, but B is zero there)

    while (tile < TILES_PER_K) {
        const int nt = tile + wstride;
        bf16x8 nA0, nA1;
        if (nt < TILES_PER_K) {   // wave-uniform branch: prefetch next tile
            int nrow = imk[nt * 16 + lo];
            nA0 = *reinterpret_cast<const bf16x8*>((const char*)fb + (size_t)nrow * 96 + hi * 16);
            nA1 = *reinterpret_cast<const bf16x8*>((const char*)fb + (size_t)nrow * 96 + 64 + hi * 16);
        }

        const int m0 = tile * 16;
        const int p0 = posk[m0 + hi * 4 + 0];
        const int p1 = posk[m0 + hi * 4 + 1];
        const int p2 = posk[m0 + hi * 4 + 2];
        const int p3 = posk[m0 + hi * 4 + 3];

        #pragma unroll
        for (int oct = 0; oct < 6; ++oct) {
            f32x4 acc = {0.f, 0.f, 0.f, 0.f};
            acc = __builtin_amdgcn_mfma_f32_16x16x32_bf16(A0, B[oct * 2 + 0], acc, 0, 0, 0);
            acc = __builtin_amdgcn_mfma_f32_16x16x32_bf16(A1, B[oct * 2 + 1], acc, 0, 0, 0);
            const int oc = oct * 16 + lo;
            contrib[(size_t)p0 * ROUT + oc] = __float2bfloat16(acc[0]);
            contrib[(size_t)p1 * ROUT + oc] = __float2bfloat16(acc[1]);
            contrib[(size_t)p2 * ROUT + oc] = __float2bfloat16(acc[2]);
            contrib[(size_t)p3 * ROUT + oc] = __float2bfloat16(acc[3]);
        }

        tile = nt;
        A0 = nA0;
        A1 = nA1;
    }
}

// ---------------------------------------------------------------------------
// Stage 2: per-row contiguous reduce over CSR slab, single write per element.
// ---------------------------------------------------------------------------
__global__ __launch_bounds__(192)
void stage2_gather(const __hip_bfloat16* __restrict__ contrib,
                   const int* __restrict__ offs,
                   float* __restrict__ out,
                   int accumulate)
{
    const int sub = threadIdx.x / 96;
    const int oc  = threadIdx.x % 96;
    const int r = blockIdx.x * 2 + sub;
    if (r >= NN) return;

    const int j0 = offs[r];
    const int j1 = offs[r + 1];
    if (j0 == j1) return;

    float acc0 = 0.f, acc1 = 0.f;
    int j = j0;
    for (; j + 1 < j1; j += 2) {
        acc0 += __bfloat162float(contrib[(size_t)j * ROUT + oc]);
        acc1 += __bfloat162float(contrib[(size_t)(j + 1) * ROUT + oc]);
    }
    if (j < j1) acc0 += __bfloat162float(contrib[(size_t)j * ROUT + oc]);

    const size_t idx = (size_t)r * ROUT + oc;
    float acc = acc0 + acc1;
    if (accumulate) out[idx] += acc;
    else            out[idx]  = acc;
}

// ---------------------------------------------------------------------------
extern "C" void kernel_launch(void* const* d_in, const int* in_sizes, int n_in,
                              void* d_out, int out_size, void* d_ws, size_t ws_size,
                              hipStream_t stream)
{
    const float* features = (const float*)d_in[0];
    const float* kernel_w = (const float*)d_in[1];
    const int*   in_map   = (const int*)d_in[2];
    const int*   out_map  = (const int*)d_in[3];
    float*       out      = (float*)d_out;

    hipMemsetAsync(d_out, 0, (size_t)out_size * sizeof(float), stream);

    // workspace layout (16B-aligned sections)
    const size_t off_cnt   = 0;                         // N ints (cnt -> cursor)
    const size_t off_offs  = 800000;                    // (N+1) ints, padded
    const size_t off_bsum  = off_offs + 800256;         // NB ints, padded
    const size_t off_fb    = off_bsum + 1024;           // N*48 bf16 = 19.2 MB
    const size_t off_wp    = off_fb + (size_t)NN * RIN * 2;   // 27*12*64*16 B
    const size_t base      = off_wp + (size_t)KK * 12 * 64 * 16;
    // per-k: pos M ints + contrib M*96 bf16
    const size_t per_k = (size_t)MM * (4 + ROUT * 2);   // 15,680,000

    int gcap = 0;
    if (ws_size > base) gcap = (int)((ws_size - base) / per_k);
    if (gcap > KK) gcap = KK;

    if (gcap < 2) {
        dim3 grid(FB_BLOCKS_PER_K, KK);
        sparse_conv_scatter<<<grid, 192, 0, stream>>>(features, kernel_w, in_map, out_map, out);
        return;
    }

    char* ws = (char*)d_ws;
    int* cnt  = (int*)(ws + off_cnt);
    int* offs = (int*)(ws + off_offs);
    int* bsum = (int*)(ws + off_bsum);
    __hip_bfloat16* fb = (__hip_bfloat16*)(ws + off_fb);
    __hip_bfloat16* wp = (__hip_bfloat16*)(ws + off_wp);

    // one-time precompute
    feat_to_bf16<<<(NN * RIN / 8 + 255) / 256, 256, 0, stream>>>(features, fb);
    build_wpack<<<KK * 12, 64, 0, stream>>>(kernel_w, wp);

    const int ngroups = (KK + gcap - 1) / gcap;

    int k0 = 0;
    for (int g = 0; g < ngroups; ++g) {
        const int gk = KK / ngroups + (g < KK % ngroups ? 1 : 0);
        const int Eg = gk * MM;
        const int* omap_base = out_map + (size_t)k0 * MM;

        int*            pos     = (int*)(ws + base);
        __hip_bfloat16* contrib = (__hip_bfloat16*)(ws + base + (size_t)gk * MM * 4);

        hipMemsetAsync(cnt, 0, (size_t)NN * sizeof(int), stream);
        count_kernel<<<(Eg + 255) / 256, 256, 0, stream>>>(omap_base, Eg, cnt);
        scan_part<<<NB_BLOCKS, 256, 0, stream>>>(cnt, bsum);
        scan_bsum<<<1, 256, 0, stream>>>(bsum);
        scan_final<<<NB_BLOCKS, 256, 0, stream>>>(cnt, bsum, offs, Eg);
        fill_kernel<<<(Eg + 255) / 256, 256, 0, stream>>>(omap_base, Eg, cnt, pos);

        dim3 g1(S1_BLOCKS_PER_K, gk);
        stage1_mfma<<<g1, 256, 0, stream>>>(fb, wp, in_map, pos, k0, contrib);

        stage2_gather<<<(NN + 1) / 2, 192, 0, stream>>>(contrib, offs, out, g > 0 ? 1 : 0);

        k0 += gk;
    }
}

// Round 6
// 600.815 us; speedup vs baseline: 4.3543x; 1.0915x over previous
//
#include <hip/hip_runtime.h>
#include <hip/hip_bf16.h>

// Problem constants (from reference setup_inputs)
#define KK   27
#define MM   80000
#define NN   200000
#define INC  64
#define OUTC 128
#define RIN  48
#define ROUT 96

// grouping: 4 groups of 7,7,7,6 kernels -> contrib slab 107.5 MB (L3-resident)
#define G        4
#define GK_BASE  (KK / G)        // 6
#define GK_REM   (KK % G)        // 3
#define GK_MAX   (GK_BASE + 1)   // 7
#define OFFS_N   200064          // (NN+1) padded to 256B

#define TILES_PER_K (MM / 16)    // 5000
#define S1_BLOCKS_PER_K 250      // 1000 waves/k, 5 tiles per wave

#define SCAN_CHUNK 1024
#define NB_BLOCKS ((NN + SCAN_CHUNK - 1) / SCAN_CHUNK)  // 196

typedef __attribute__((ext_vector_type(8))) short bf16x8;  // 8 bf16 = 4 VGPR
typedef __attribute__((ext_vector_type(4))) float f32x4;

__device__ __forceinline__ float bf2f(short s) {
    return __uint_as_float(((unsigned)(unsigned short)s) << 16);
}
__device__ __forceinline__ int group_of_k(int k) {
    return (k < (GK_BASE + 1) * GK_REM) ? (k / (GK_BASE + 1))
                                        : GK_REM + (k - (GK_BASE + 1) * GK_REM) / GK_BASE;
}

// ---------------------------------------------------------------------------
// Fallback: single-pass atomic scatter (R1 kernel, known-good, ~1.66 ms)
// ---------------------------------------------------------------------------
#define FB_BLOCKS_PER_K 200
#define FB_ENTRIES_PER_BLOCK ((MM + FB_BLOCKS_PER_K - 1) / FB_BLOCKS_PER_K)

__global__ __launch_bounds__(192)
void sparse_conv_scatter(const float* __restrict__ feat,
                         const float* __restrict__ w,
                         const int* __restrict__ imap,
                         const int* __restrict__ omap,
                         float* __restrict__ out)
{
    __shared__ float wlds[RIN * ROUT];
    const int k = blockIdx.y;
    const float* wk = w + (size_t)k * INC * OUTC;
    for (int idx = threadIdx.x; idx < RIN * ROUT; idx += 192) {
        int i = idx / ROUT;
        int o = idx - i * ROUT;
        wlds[idx] = wk[i * OUTC + o];
    }
    __syncthreads();

    const int sub = threadIdx.x / 96;
    const int oc  = threadIdx.x % 96;
    const int m0 = blockIdx.x * FB_ENTRIES_PER_BLOCK;
    const int m1 = min(m0 + FB_ENTRIES_PER_BLOCK, MM);
    const int* imk = imap + (size_t)k * MM;
    const int* omk = omap + (size_t)k * MM;

    for (int m = m0 + sub; m < m1; m += 2) {
        const int fin  = imk[m];
        const int fout = omk[m];
        const float4* f4 = (const float4*)(feat + (size_t)fin * RIN);
        float acc = 0.f;
        #pragma unroll
        for (int i4 = 0; i4 < RIN / 4; ++i4) {
            float4 v = f4[i4];
            acc += v.x * wlds[(i4 * 4 + 0) * ROUT + oc];
            acc += v.y * wlds[(i4 * 4 + 1) * ROUT + oc];
            acc += v.z * wlds[(i4 * 4 + 2) * ROUT + oc];
            acc += v.w * wlds[(i4 * 4 + 3) * ROUT + oc];
        }
        atomicAdd(&out[(size_t)fout * ROUT + oc], acc);
    }
}

// ---------------------------------------------------------------------------
// Precompute: features -> bf16, weights -> MFMA B-fragment pack
// ---------------------------------------------------------------------------
__global__ __launch_bounds__(256)
void feat_to_bf16(const float* __restrict__ f, __hip_bfloat16* __restrict__ fb)
{
    const size_t i = (size_t)blockIdx.x * 256 + threadIdx.x;   // one per 8 elems
    if (i >= (size_t)NN * RIN / 8) return;
    const float4* p = (const float4*)(f + i * 8);
    float4 a = p[0], b = p[1];
    union { __hip_bfloat16 h[8]; uint4 v; } o;
    o.h[0] = __float2bfloat16(a.x);
    o.h[1] = __float2bfloat16(a.y);
    o.h[2] = __float2bfloat16(a.z);
    o.h[3] = __float2bfloat16(a.w);
    o.h[4] = __float2bfloat16(b.x);
    o.h[5] = __float2bfloat16(b.y);
    o.h[6] = __float2bfloat16(b.z);
    o.h[7] = __float2bfloat16(b.w);
    ((uint4*)fb)[i] = o.v;
}

// wpack: frag f = oct*2 + ktile of kernel k at ((k*12 + f)*64 + lane)*16 bytes
__global__ __launch_bounds__(64)
void build_wpack(const float* __restrict__ w, __hip_bfloat16* __restrict__ wp)
{
    const int b = blockIdx.x;          // k*12 + f
    const int k = b / 12;
    const int f = b % 12;
    const int oct = f / 2, ktile = f % 2;
    const int lane = threadIdx.x;
    const int oc    = oct * 16 + (lane & 15);
    const int kbase = ktile * 32 + (lane >> 4) * 8;
    union { __hip_bfloat16 h[8]; uint4 v; } o;
    #pragma unroll
    for (int j = 0; j < 8; ++j) {
        int ki = kbase + j;
        float val = (ki < RIN) ? w[(size_t)k * INC * OUTC + (size_t)ki * OUTC + oc] : 0.f;
        o.h[j] = __float2bfloat16(val);
    }
    ((uint4*)wp)[(size_t)b * 64 + lane] = o.v;
}

// ---------------------------------------------------------------------------
// CSR build (ALL groups in one pass)
// ---------------------------------------------------------------------------
__global__ __launch_bounds__(256)
void count_all(const int* __restrict__ omap, int* __restrict__ cnt)
{
    int e = blockIdx.x * 256 + threadIdx.x;
    if (e >= KK * MM) return;
    int k = e / MM;
    int g = group_of_k(k);
    atomicAdd(&cnt[(size_t)g * NN + omap[e]], 1);
}

__global__ __launch_bounds__(256)
void scan_part(const int* __restrict__ cnt, int* __restrict__ bsum)
{
    __shared__ int sh[256];
    const int g = blockIdx.y;
    const int* c = cnt + (size_t)g * NN;
    int t = threadIdx.x;
    int base = blockIdx.x * SCAN_CHUNK + t * 4;
    int s = 0;
    #pragma unroll
    for (int j = 0; j < 4; ++j)
        if (base + j < NN) s += c[base + j];
    sh[t] = s;
    __syncthreads();
    for (int off = 128; off > 0; off >>= 1) {
        if (t < off) sh[t] += sh[t + off];
        __syncthreads();
    }
    if (t == 0) bsum[g * 256 + blockIdx.x] = sh[0];
}

__global__ __launch_bounds__(256)
void scan_bsum(int* __restrict__ bsum)
{
    __shared__ int sh[256];
    const int g = blockIdx.x;
    int* b = bsum + g * 256;
    int t = threadIdx.x;
    int v = (t < NB_BLOCKS) ? b[t] : 0;
    sh[t] = v;
    __syncthreads();
    for (int off = 1; off < 256; off <<= 1) {
        int x = (t >= off) ? sh[t - off] : 0;
        __syncthreads();
        sh[t] += x;
        __syncthreads();
    }
    if (t < NB_BLOCKS) b[t] = sh[t] - v;   // exclusive
}

__global__ __launch_bounds__(256)
void scan_final(int* __restrict__ cnt /*-> cursor*/,
                const int* __restrict__ bsum,
                int* __restrict__ offs)
{
    __shared__ int sh[256];
    const int g = blockIdx.y;
    int* c = cnt + (size_t)g * NN;
    int* o = offs + (size_t)g * OFFS_N;
    int t = threadIdx.x;
    int base = blockIdx.x * SCAN_CHUNK + t * 4;
    int v[4];
    int s = 0;
    #pragma unroll
    for (int j = 0; j < 4; ++j) {
        v[j] = (base + j < NN) ? c[base + j] : 0;
        s += v[j];
    }
    sh[t] = s;
    __syncthreads();
    for (int off = 1; off < 256; off <<= 1) {
        int x = (t >= off) ? sh[t - off] : 0;
        __syncthreads();
        sh[t] += x;
        __syncthreads();
    }
    int run = sh[t] - s + bsum[g * 256 + blockIdx.x];
    #pragma unroll
    for (int j = 0; j < 4; ++j) {
        if (base + j < NN) {
            o[base + j] = run;
            c[base + j] = run;   // cursor
            run += v[j];
        }
    }
    if (blockIdx.x == 0 && t == 0) {
        int gk = GK_BASE + (g < GK_REM ? 1 : 0);
        o[NN] = gk * MM;
    }
}

__global__ __launch_bounds__(256)
void fill_all(const int* __restrict__ omap,
              int* __restrict__ cursor, int* __restrict__ pos)
{
    int e = blockIdx.x * 256 + threadIdx.x;
    if (e >= KK * MM) return;
    int k = e / MM;
    int g = group_of_k(k);
    int r = omap[e];
    pos[e] = atomicAdd(&cursor[(size_t)g * NN + r], 1);
}

// ---------------------------------------------------------------------------
// Stage 1 (MFMA): 16-entry x 96-oc contribution tiles, written in CSR order.
// ---------------------------------------------------------------------------
__global__ __launch_bounds__(256)
void stage1_mfma(const __hip_bfloat16* __restrict__ fb,
                 const __hip_bfloat16* __restrict__ wp,
                 const int* __restrict__ imap,
                 const int* __restrict__ pos,
                 int k0,
                 __hip_bfloat16* __restrict__ contrib)
{
    const int k = k0 + blockIdx.y;
    const int wid  = threadIdx.x >> 6;
    const int lane = threadIdx.x & 63;
    const int lo = lane & 15, hi = lane >> 4;

    bf16x8 B[12];
    #pragma unroll
    for (int f = 0; f < 12; ++f)
        B[f] = *reinterpret_cast<const bf16x8*>(
            (const char*)wp + (((size_t)k * 12 + f) * 64 + lane) * 16);

    const int* imk  = imap + (size_t)k * MM;
    const int* posk = pos + (size_t)k * MM;

    const int wstride = gridDim.x * 4;
    int tile = blockIdx.x * 4 + wid;
    if (tile >= TILES_PER_K) return;

    int row = imk[tile * 16 + lo];
    bf16x8 A0 = *reinterpret_cast<const bf16x8*>((const char*)fb + (size_t)row * 96 + hi * 16);
    bf16x8 A1 = *reinterpret_cast<const bf16x8*>((const char*)fb + (size_t)row * 96 + 64 + hi * 16);

    while (tile < TILES_PER_K) {
        const int nt = tile + wstride;
        bf16x8 nA0, nA1;
        if (nt < TILES_PER_K) {   // wave-uniform prefetch of next tile
            int nrow = imk[nt * 16 + lo];
            nA0 = *reinterpret_cast<const bf16x8*>((const char*)fb + (size_t)nrow * 96 + hi * 16);
            nA1 = *reinterpret_cast<const bf16x8*>((const char*)fb + (size_t)nrow * 96 + 64 + hi * 16);
        }

        const int m0 = tile * 16;
        const int p0 = posk[m0 + hi * 4 + 0];
        const int p1 = posk[m0 + hi * 4 + 1];
        const int p2 = posk[m0 + hi * 4 + 2];
        const int p3 = posk[m0 + hi * 4 + 3];

        #pragma unroll
        for (int oct = 0; oct < 6; ++oct) {
            f32x4 acc = {0.f, 0.f, 0.f, 0.f};
            acc = __builtin_amdgcn_mfma_f32_16x16x32_bf16(A0, B[oct * 2 + 0], acc, 0, 0, 0);
            acc = __builtin_amdgcn_mfma_f32_16x16x32_bf16(A1, B[oct * 2 + 1], acc, 0, 0, 0);
            const int oc = oct * 16 + lo;
            contrib[(size_t)p0 * ROUT + oc] = __float2bfloat16(acc[0]);
            contrib[(size_t)p1 * ROUT + oc] = __float2bfloat16(acc[1]);
            contrib[(size_t)p2 * ROUT + oc] = __float2bfloat16(acc[2]);
            contrib[(size_t)p3 * ROUT + oc] = __float2bfloat16(acc[3]);
        }

        tile = nt;
        A0 = nA0;
        A1 = nA1;
    }
}

// ---------------------------------------------------------------------------
// Stage 2: one WAVE per output row. lane = jj(0..3) x ocg(0..11 of 16).
// 16B bf16x8 loads, 4-way j-parallel, shfl reduce, float4-pair write.
// ---------------------------------------------------------------------------
__global__ __launch_bounds__(256)
void stage2_gather(const __hip_bfloat16* __restrict__ contrib,
                   const int* __restrict__ offs,
                   float* __restrict__ out,
                   int accumulate)
{
    const int wid  = threadIdx.x >> 6;
    const int lane = threadIdx.x & 63;
    const int r = blockIdx.x * 4 + wid;
    if (r >= NN) return;

    const int jj  = lane >> 4;    // 0..3
    const int ocg = lane & 15;    // 0..15 (active < 12)

    const int j0 = offs[r];
    const int j1 = offs[r + 1];
    if (j0 == j1) return;

    f32x4 accA = {0.f, 0.f, 0.f, 0.f};
    f32x4 accB = {0.f, 0.f, 0.f, 0.f};
    if (ocg < 12) {
        for (int j = j0 + jj; j < j1; j += 4) {
            bf16x8 v = *reinterpret_cast<const bf16x8*>(contrib + (size_t)j * ROUT + ocg * 8);
            accA[0] += bf2f(v[0]); accA[1] += bf2f(v[1]);
            accA[2] += bf2f(v[2]); accA[3] += bf2f(v[3]);
            accB[0] += bf2f(v[4]); accB[1] += bf2f(v[5]);
            accB[2] += bf2f(v[6]); accB[3] += bf2f(v[7]);
        }
    }
    #pragma unroll
    for (int i = 0; i < 4; ++i) {
        accA[i] += __shfl_down(accA[i], 32);
        accB[i] += __shfl_down(accB[i], 32);
    }
    #pragma unroll
    for (int i = 0; i < 4; ++i) {
        accA[i] += __shfl_down(accA[i], 16);
        accB[i] += __shfl_down(accB[i], 16);
    }
    if (lane < 12) {
        float4* o = (float4*)(out + (size_t)r * ROUT + lane * 8);
        float4 x0 = {accA[0], accA[1], accA[2], accA[3]};
        float4 x1 = {accB[0], accB[1], accB[2], accB[3]};
        if (accumulate) {
            float4 y0 = o[0], y1 = o[1];
            x0.x += y0.x; x0.y += y0.y; x0.z += y0.z; x0.w += y0.w;
            x1.x += y1.x; x1.y += y1.y; x1.z += y1.z; x1.w += y1.w;
        }
        o[0] = x0; o[1] = x1;
    }
}

// ---------------------------------------------------------------------------
extern "C" void kernel_launch(void* const* d_in, const int* in_sizes, int n_in,
                              void* d_out, int out_size, void* d_ws, size_t ws_size,
                              hipStream_t stream)
{
    const float* features = (const float*)d_in[0];
    const float* kernel_w = (const float*)d_in[1];
    const int*   in_map   = (const int*)d_in[2];
    const int*   out_map  = (const int*)d_in[3];
    float*       out      = (float*)d_out;

    hipMemsetAsync(d_out, 0, (size_t)out_size * sizeof(float), stream);

    // workspace layout (all 16B-aligned)
    const size_t off_cnt     = 0;                                   // G*NN ints
    const size_t off_offs    = off_cnt  + (size_t)G * NN * 4;       // G*OFFS_N ints
    const size_t off_bsum    = off_offs + (size_t)G * OFFS_N * 4;   // G*256 ints
    const size_t off_fb      = off_bsum + (size_t)G * 1024;         // NN*RIN bf16
    const size_t off_wp      = off_fb   + (size_t)NN * RIN * 2;     // KK*12*64*16 B
    const size_t off_pos     = off_wp   + (size_t)KK * 12 * 64 * 16;// KK*MM ints
    const size_t off_contrib = off_pos  + (size_t)KK * MM * 4;      // GK_MAX*MM*96 bf16
    const size_t total_ws    = off_contrib + (size_t)GK_MAX * MM * ROUT * 2;

    if (ws_size < total_ws) {
        dim3 grid(FB_BLOCKS_PER_K, KK);
        sparse_conv_scatter<<<grid, 192, 0, stream>>>(features, kernel_w, in_map, out_map, out);
        return;
    }

    char* ws = (char*)d_ws;
    int* cnt  = (int*)(ws + off_cnt);
    int* offs = (int*)(ws + off_offs);
    int* bsum = (int*)(ws + off_bsum);
    __hip_bfloat16* fb = (__hip_bfloat16*)(ws + off_fb);
    __hip_bfloat16* wp = (__hip_bfloat16*)(ws + off_wp);
    int* pos = (int*)(ws + off_pos);
    __hip_bfloat16* contrib = (__hip_bfloat16*)(ws + off_contrib);

    // one-time precompute
    feat_to_bf16<<<(NN * RIN / 8 + 255) / 256, 256, 0, stream>>>(features, fb);
    build_wpack<<<KK * 12, 64, 0, stream>>>(kernel_w, wp);

    // build ALL CSR structures in one pass
    hipMemsetAsync(cnt, 0, (size_t)G * NN * sizeof(int), stream);
    const int EBLK = (KK * MM + 255) / 256;
    count_all<<<EBLK, 256, 0, stream>>>(out_map, cnt);
    {
        dim3 gp(NB_BLOCKS, G);
        scan_part<<<gp, 256, 0, stream>>>(cnt, bsum);
        scan_bsum<<<G, 256, 0, stream>>>(bsum);
        scan_final<<<gp, 256, 0, stream>>>(cnt, bsum, offs);
    }
    fill_all<<<EBLK, 256, 0, stream>>>(out_map, cnt, pos);

    // per-group: MFMA compute into L3-resident contrib, then gather-reduce
    for (int g = 0; g < G; ++g) {
        const int k0 = g * GK_BASE + (g < GK_REM ? g : GK_REM);
        const int gk = GK_BASE + (g < GK_REM ? 1 : 0);

        dim3 g1(S1_BLOCKS_PER_K, gk);
        stage1_mfma<<<g1, 256, 0, stream>>>(fb, wp, in_map, pos, k0, contrib);

        stage2_gather<<<NN / 4, 256, 0, stream>>>(contrib, offs + (size_t)g * OFFS_N,
                                                  out, g > 0 ? 1 : 0);
    }
}

// Round 7
// 463.565 us; speedup vs baseline: 5.6436x; 1.2961x over previous
//
#include <hip/hip_runtime.h>
#include <hip/hip_bf16.h>

// Problem constants (from reference setup_inputs)
#define KK   27
#define MM   80000
#define NN   200000
#define INC  64
#define OUTC 128
#define RIN  48
#define ROUT 96

// grouping: 4 groups of 7,7,7,6 kernels -> contrib slab <=107.5 MB (L3-resident)
#define G        4
#define GK_BASE  (KK / G)        // 6
#define GK_REM   (KK % G)        // 3
#define GK_MAX   (GK_BASE + 1)   // 7
#define OFFS_N   200064          // (NN+1) padded to 256B

#define TILES_PER_K (MM / 16)    // 5000
#define S1_BLOCKS_PER_K 250      // 1000 waves/k, 5 tiles per wave

#define SCAN_CHUNK 1024
#define NB_BLOCKS ((NN + SCAN_CHUNK - 1) / SCAN_CHUNK)  // 196

typedef __attribute__((ext_vector_type(8))) short bf16x8;  // 8 bf16 = 4 VGPR
typedef __attribute__((ext_vector_type(4))) float f32x4;

__device__ __forceinline__ float bf2f(short s) {
    return __uint_as_float(((unsigned)(unsigned short)s) << 16);
}
__device__ __forceinline__ int group_of_k(int k) {
    return (k < (GK_BASE + 1) * GK_REM) ? (k / (GK_BASE + 1))
                                        : GK_REM + (k - (GK_BASE + 1) * GK_REM) / GK_BASE;
}

// ---------------------------------------------------------------------------
// Fallback: single-pass atomic scatter (R1 kernel, known-good, ~1.66 ms)
// ---------------------------------------------------------------------------
#define FB_BLOCKS_PER_K 200
#define FB_ENTRIES_PER_BLOCK ((MM + FB_BLOCKS_PER_K - 1) / FB_BLOCKS_PER_K)

__global__ __launch_bounds__(192)
void sparse_conv_scatter(const float* __restrict__ feat,
                         const float* __restrict__ w,
                         const int* __restrict__ imap,
                         const int* __restrict__ omap,
                         float* __restrict__ out)
{
    __shared__ float wlds[RIN * ROUT];
    const int k = blockIdx.y;
    const float* wk = w + (size_t)k * INC * OUTC;
    for (int idx = threadIdx.x; idx < RIN * ROUT; idx += 192) {
        int i = idx / ROUT;
        int o = idx - i * ROUT;
        wlds[idx] = wk[i * OUTC + o];
    }
    __syncthreads();

    const int sub = threadIdx.x / 96;
    const int oc  = threadIdx.x % 96;
    const int m0 = blockIdx.x * FB_ENTRIES_PER_BLOCK;
    const int m1 = min(m0 + FB_ENTRIES_PER_BLOCK, MM);
    const int* imk = imap + (size_t)k * MM;
    const int* omk = omap + (size_t)k * MM;

    for (int m = m0 + sub; m < m1; m += 2) {
        const int fin  = imk[m];
        const int fout = omk[m];
        const float4* f4 = (const float4*)(feat + (size_t)fin * RIN);
        float acc = 0.f;
        #pragma unroll
        for (int i4 = 0; i4 < RIN / 4; ++i4) {
            float4 v = f4[i4];
            acc += v.x * wlds[(i4 * 4 + 0) * ROUT + oc];
            acc += v.y * wlds[(i4 * 4 + 1) * ROUT + oc];
            acc += v.z * wlds[(i4 * 4 + 2) * ROUT + oc];
            acc += v.w * wlds[(i4 * 4 + 3) * ROUT + oc];
        }
        atomicAdd(&out[(size_t)fout * ROUT + oc], acc);
    }
}

// ---------------------------------------------------------------------------
// Precompute: features -> bf16, weights -> MFMA B-fragment pack
// ---------------------------------------------------------------------------
__global__ __launch_bounds__(256)
void feat_to_bf16(const float* __restrict__ f, __hip_bfloat16* __restrict__ fb)
{
    const size_t i = (size_t)blockIdx.x * 256 + threadIdx.x;   // one per 8 elems
    if (i >= (size_t)NN * RIN / 8) return;
    const float4* p = (const float4*)(f + i * 8);
    float4 a = p[0], b = p[1];
    union { __hip_bfloat16 h[8]; uint4 v; } o;
    o.h[0] = __float2bfloat16(a.x);
    o.h[1] = __float2bfloat16(a.y);
    o.h[2] = __float2bfloat16(a.z);
    o.h[3] = __float2bfloat16(a.w);
    o.h[4] = __float2bfloat16(b.x);
    o.h[5] = __float2bfloat16(b.y);
    o.h[6] = __float2bfloat16(b.z);
    o.h[7] = __float2bfloat16(b.w);
    ((uint4*)fb)[i] = o.v;
}

// wpack: frag f = oct*2 + ktile of kernel k at ((k*12 + f)*64 + lane)*16 bytes
__global__ __launch_bounds__(64)
void build_wpack(const float* __restrict__ w, __hip_bfloat16* __restrict__ wp)
{
    const int b = blockIdx.x;          // k*12 + f
    const int k = b / 12;
    const int f = b % 12;
    const int oct = f / 2, ktile = f % 2;
    const int lane = threadIdx.x;
    const int oc    = oct * 16 + (lane & 15);
    const int kbase = ktile * 32 + (lane >> 4) * 8;
    union { __hip_bfloat16 h[8]; uint4 v; } o;
    #pragma unroll
    for (int j = 0; j < 8; ++j) {
        int ki = kbase + j;
        float val = (ki < RIN) ? w[(size_t)k * INC * OUTC + (size_t)ki * OUTC + oc] : 0.f;
        o.h[j] = __float2bfloat16(val);
    }
    ((uint4*)wp)[(size_t)b * 64 + lane] = o.v;
}

// ---------------------------------------------------------------------------
// CSR build: ONE atomic pass. posl[e] = local slot within (group,row) bucket;
// cursor ends holding the per-(group,row) counts, which are then scanned.
// ---------------------------------------------------------------------------
__global__ __launch_bounds__(256)
void fill_local(const int* __restrict__ omap,
                int* __restrict__ cursor, int* __restrict__ posl)
{
    int e = blockIdx.x * 256 + threadIdx.x;
    if (e >= KK * MM) return;
    int k = e / MM;
    int g = group_of_k(k);
    int r = omap[e];
    posl[e] = atomicAdd(&cursor[(size_t)g * NN + r], 1);
}

__global__ __launch_bounds__(256)
void scan_part(const int* __restrict__ cnt, int* __restrict__ bsum)
{
    __shared__ int sh[256];
    const int g = blockIdx.y;
    const int* c = cnt + (size_t)g * NN;
    int t = threadIdx.x;
    int base = blockIdx.x * SCAN_CHUNK + t * 4;
    int s = 0;
    #pragma unroll
    for (int j = 0; j < 4; ++j)
        if (base + j < NN) s += c[base + j];
    sh[t] = s;
    __syncthreads();
    for (int off = 128; off > 0; off >>= 1) {
        if (t < off) sh[t] += sh[t + off];
        __syncthreads();
    }
    if (t == 0) bsum[g * 256 + blockIdx.x] = sh[0];
}

__global__ __launch_bounds__(256)
void scan_bsum(int* __restrict__ bsum)
{
    __shared__ int sh[256];
    const int g = blockIdx.x;
    int* b = bsum + g * 256;
    int t = threadIdx.x;
    int v = (t < NB_BLOCKS) ? b[t] : 0;
    sh[t] = v;
    __syncthreads();
    for (int off = 1; off < 256; off <<= 1) {
        int x = (t >= off) ? sh[t - off] : 0;
        __syncthreads();
        sh[t] += x;
        __syncthreads();
    }
    if (t < NB_BLOCKS) b[t] = sh[t] - v;   // exclusive
}

__global__ __launch_bounds__(256)
void scan_final(const int* __restrict__ cnt,
                const int* __restrict__ bsum,
                int* __restrict__ offs)
{
    __shared__ int sh[256];
    const int g = blockIdx.y;
    const int* c = cnt + (size_t)g * NN;
    int* o = offs + (size_t)g * OFFS_N;
    int t = threadIdx.x;
    int base = blockIdx.x * SCAN_CHUNK + t * 4;
    int v[4];
    int s = 0;
    #pragma unroll
    for (int j = 0; j < 4; ++j) {
        v[j] = (base + j < NN) ? c[base + j] : 0;
        s += v[j];
    }
    sh[t] = s;
    __syncthreads();
    for (int off = 1; off < 256; off <<= 1) {
        int x = (t >= off) ? sh[t - off] : 0;
        __syncthreads();
        sh[t] += x;
        __syncthreads();
    }
    int run = sh[t] - s + bsum[g * 256 + blockIdx.x];
    #pragma unroll
    for (int j = 0; j < 4; ++j) {
        if (base + j < NN) {
            o[base + j] = run;
            run += v[j];
        }
    }
    if (blockIdx.x == 0 && t == 0) {
        int gk = GK_BASE + (g < GK_REM ? 1 : 0);
        o[NN] = gk * MM;
    }
}

// ---------------------------------------------------------------------------
// Stage 1 (MFMA): 16-entry x 96-oc contribution tiles, written in CSR order.
// Slot = offs_g[omap[e]] + posl[e].
// ---------------------------------------------------------------------------
__global__ __launch_bounds__(256)
void stage1_mfma(const __hip_bfloat16* __restrict__ fb,
                 const __hip_bfloat16* __restrict__ wp,
                 const int* __restrict__ imap,
                 const int* __restrict__ omap,
                 const int* __restrict__ posl,
                 const int* __restrict__ offs_g,
                 int k0,
                 __hip_bfloat16* __restrict__ contrib)
{
    const int k = k0 + blockIdx.y;
    const int wid  = threadIdx.x >> 6;
    const int lane = threadIdx.x & 63;
    const int lo = lane & 15, hi = lane >> 4;

    bf16x8 B[12];
    #pragma unroll
    for (int f = 0; f < 12; ++f)
        B[f] = *reinterpret_cast<const bf16x8*>(
            (const char*)wp + (((size_t)k * 12 + f) * 64 + lane) * 16);

    const int* imk = imap + (size_t)k * MM;
    const int* omk = omap + (size_t)k * MM;
    const int* plk = posl + (size_t)k * MM;

    const int wstride = gridDim.x * 4;
    int tile = blockIdx.x * 4 + wid;
    if (tile >= TILES_PER_K) return;

    int row = imk[tile * 16 + lo];
    bf16x8 A0 = *reinterpret_cast<const bf16x8*>((const char*)fb + (size_t)row * 96 + hi * 16);
    bf16x8 A1 = *reinterpret_cast<const bf16x8*>((const char*)fb + (size_t)row * 96 + 64 + hi * 16);

    while (tile < TILES_PER_K) {
        const int nt = tile + wstride;
        bf16x8 nA0, nA1;
        if (nt < TILES_PER_K) {   // wave-uniform prefetch of next tile
            int nrow = imk[nt * 16 + lo];
            nA0 = *reinterpret_cast<const bf16x8*>((const char*)fb + (size_t)nrow * 96 + hi * 16);
            nA1 = *reinterpret_cast<const bf16x8*>((const char*)fb + (size_t)nrow * 96 + 64 + hi * 16);
        }

        const int m = tile * 16 + hi * 4;
        const int r0 = omk[m + 0], r1 = omk[m + 1], r2 = omk[m + 2], r3 = omk[m + 3];
        const int p0 = offs_g[r0] + plk[m + 0];
        const int p1 = offs_g[r1] + plk[m + 1];
        const int p2 = offs_g[r2] + plk[m + 2];
        const int p3 = offs_g[r3] + plk[m + 3];

        #pragma unroll
        for (int oct = 0; oct < 6; ++oct) {
            f32x4 acc = {0.f, 0.f, 0.f, 0.f};
            acc = __builtin_amdgcn_mfma_f32_16x16x32_bf16(A0, B[oct * 2 + 0], acc, 0, 0, 0);
            acc = __builtin_amdgcn_mfma_f32_16x16x32_bf16(A1, B[oct * 2 + 1], acc, 0, 0, 0);
            const int oc = oct * 16 + lo;
            contrib[(size_t)p0 * ROUT + oc] = __float2bfloat16(acc[0]);
            contrib[(size_t)p1 * ROUT + oc] = __float2bfloat16(acc[1]);
            contrib[(size_t)p2 * ROUT + oc] = __float2bfloat16(acc[2]);
            contrib[(size_t)p3 * ROUT + oc] = __float2bfloat16(acc[3]);
        }

        tile = nt;
        A0 = nA0;
        A1 = nA1;
    }
}

// ---------------------------------------------------------------------------
// Stage 2: each wave handles 4 rows; lane = (row-sub, ocg). Active lanes
// (ocg<12) each own 8 channels: serial j loop, 16B loads, no cross-lane ops.
// ---------------------------------------------------------------------------
__global__ __launch_bounds__(256)
void stage2_gather(const __hip_bfloat16* __restrict__ contrib,
                   const int* __restrict__ offs,
                   float* __restrict__ out,
                   int accumulate)
{
    const int lane = threadIdx.x & 63;
    const int sub  = lane >> 4;     // 0..3 row within wave
    const int ocg  = lane & 15;     // 0..15, active < 12
    const int r = blockIdx.x * 16 + (threadIdx.x >> 6) * 4 + sub;
    if (r >= NN) return;

    const int j0 = offs[r];
    const int j1 = offs[r + 1];
    if (j0 == j1 || ocg >= 12) return;   // g=0: out pre-zeroed by memset

    f32x4 accA = {0.f, 0.f, 0.f, 0.f};
    f32x4 accB = {0.f, 0.f, 0.f, 0.f};
    int j = j0;
    for (; j + 1 < j1; j += 2) {
        bf16x8 v0 = *reinterpret_cast<const bf16x8*>(contrib + (size_t)j * ROUT + ocg * 8);
        bf16x8 v1 = *reinterpret_cast<const bf16x8*>(contrib + (size_t)(j + 1) * ROUT + ocg * 8);
        accA[0] += bf2f(v0[0]); accA[1] += bf2f(v0[1]);
        accA[2] += bf2f(v0[2]); accA[3] += bf2f(v0[3]);
        accB[0] += bf2f(v0[4]); accB[1] += bf2f(v0[5]);
        accB[2] += bf2f(v0[6]); accB[3] += bf2f(v0[7]);
        accA[0] += bf2f(v1[0]); accA[1] += bf2f(v1[1]);
        accA[2] += bf2f(v1[2]); accA[3] += bf2f(v1[3]);
        accB[0] += bf2f(v1[4]); accB[1] += bf2f(v1[5]);
        accB[2] += bf2f(v1[6]); accB[3] += bf2f(v1[7]);
    }
    if (j < j1) {
        bf16x8 v0 = *reinterpret_cast<const bf16x8*>(contrib + (size_t)j * ROUT + ocg * 8);
        accA[0] += bf2f(v0[0]); accA[1] += bf2f(v0[1]);
        accA[2] += bf2f(v0[2]); accA[3] += bf2f(v0[3]);
        accB[0] += bf2f(v0[4]); accB[1] += bf2f(v0[5]);
        accB[2] += bf2f(v0[6]); accB[3] += bf2f(v0[7]);
    }

    float4* o = (float4*)(out + (size_t)r * ROUT + ocg * 8);
    float4 x0 = {accA[0], accA[1], accA[2], accA[3]};
    float4 x1 = {accB[0], accB[1], accB[2], accB[3]};
    if (accumulate) {
        float4 y0 = o[0], y1 = o[1];
        x0.x += y0.x; x0.y += y0.y; x0.z += y0.z; x0.w += y0.w;
        x1.x += y1.x; x1.y += y1.y; x1.z += y1.z; x1.w += y1.w;
    }
    o[0] = x0; o[1] = x1;
}

// ---------------------------------------------------------------------------
extern "C" void kernel_launch(void* const* d_in, const int* in_sizes, int n_in,
                              void* d_out, int out_size, void* d_ws, size_t ws_size,
                              hipStream_t stream)
{
    const float* features = (const float*)d_in[0];
    const float* kernel_w = (const float*)d_in[1];
    const int*   in_map   = (const int*)d_in[2];
    const int*   out_map  = (const int*)d_in[3];
    float*       out      = (float*)d_out;

    hipMemsetAsync(d_out, 0, (size_t)out_size * sizeof(float), stream);

    // workspace layout (all 16B-aligned)
    const size_t off_cnt     = 0;                                   // G*NN ints
    const size_t off_offs    = off_cnt  + (size_t)G * NN * 4;       // G*OFFS_N ints
    const size_t off_bsum    = off_offs + (size_t)G * OFFS_N * 4;   // G*256 ints
    const size_t off_fb      = off_bsum + (size_t)G * 1024;         // NN*RIN bf16
    const size_t off_wp      = off_fb   + (size_t)NN * RIN * 2;     // KK*12*64*16 B
    const size_t off_pos     = off_wp   + (size_t)KK * 12 * 64 * 16;// KK*MM ints
    const size_t off_contrib = off_pos  + (size_t)KK * MM * 4;      // GK_MAX*MM*96 bf16
    const size_t total_ws    = off_contrib + (size_t)GK_MAX * MM * ROUT * 2;

    if (ws_size < total_ws) {
        dim3 grid(FB_BLOCKS_PER_K, KK);
        sparse_conv_scatter<<<grid, 192, 0, stream>>>(features, kernel_w, in_map, out_map, out);
        return;
    }

    char* ws = (char*)d_ws;
    int* cnt  = (int*)(ws + off_cnt);
    int* offs = (int*)(ws + off_offs);
    int* bsum = (int*)(ws + off_bsum);
    __hip_bfloat16* fb = (__hip_bfloat16*)(ws + off_fb);
    __hip_bfloat16* wp = (__hip_bfloat16*)(ws + off_wp);
    int* posl = (int*)(ws + off_pos);
    __hip_bfloat16* contrib = (__hip_bfloat16*)(ws + off_contrib);

    // one-time precompute
    hipMemsetAsync(cnt, 0, (size_t)G * NN * sizeof(int), stream);
    feat_to_bf16<<<(NN * RIN / 8 + 255) / 256, 256, 0, stream>>>(features, fb);
    build_wpack<<<KK * 12, 64, 0, stream>>>(kernel_w, wp);

    // single atomic pass: local slot + counts, then scan counts -> offs
    const int EBLK = (KK * MM + 255) / 256;
    fill_local<<<EBLK, 256, 0, stream>>>(out_map, cnt, posl);
    {
        dim3 gp(NB_BLOCKS, G);
        scan_part<<<gp, 256, 0, stream>>>(cnt, bsum);
        scan_bsum<<<G, 256, 0, stream>>>(bsum);
        scan_final<<<gp, 256, 0, stream>>>(cnt, bsum, offs);
    }

    // per-group: MFMA compute into L3-resident contrib, then gather-reduce
    for (int g = 0; g < G; ++g) {
        const int k0 = g * GK_BASE + (g < GK_REM ? g : GK_REM);
        const int gk = GK_BASE + (g < GK_REM ? 1 : 0);
        const int* offs_g = offs + (size_t)g * OFFS_N;

        dim3 g1(S1_BLOCKS_PER_K, gk);
        stage1_mfma<<<g1, 256, 0, stream>>>(fb, wp, in_map, out_map, posl, offs_g, k0, contrib);

        stage2_gather<<<(NN + 15) / 16, 256, 0, stream>>>(contrib, offs_g, out, g > 0 ? 1 : 0);
    }
}